// Round 10
// baseline (395.199 us; speedup 1.0000x reference)
//
#include <hip/hip_runtime.h>
#include <math.h>

#define BATCH 8
#define NN 2048
#define FF 128

typedef __attribute__((ext_vector_type(4))) float f32x4;
typedef _Float16 half8 __attribute__((ext_vector_type(8)));

__device__ __forceinline__ unsigned short h2u(_Float16 h) {
    return __builtin_bit_cast(unsigned short, h);
}

// ---------------------------------------------------------------------------
// k_h: h = x@W via fp16-split MFMA (xh*Wh + xl*Wh + xh*Wl) with W fragments
// derived IN-REGISTER from fp32 W (no prep kernel; W is L2-resident).
// 1024 blocks x 256 thr = 4 blocks/CU: block = 16 rows x 128 cols; wave =
// 16 rows x 32 cols (2 ntiles). h stored as one fp16 plane in B-frag layout;
// epilogue: factored exponentials Sg/S2g/Eg/E2g.
// Also: each block packs 2 adj rows -> transposed bitmask amT[jw][i] (ballot),
// and block 0 zeroes the k_attn merge counters.
// ---------------------------------------------------------------------------
__global__ __launch_bounds__(256) void k_h(const float* __restrict__ x,
                                           const int* __restrict__ adj,
                                           const float* __restrict__ W,
                                           const float* __restrict__ a_src,
                                           const float* __restrict__ a_dst,
                                           unsigned short* __restrict__ hF,
                                           float* __restrict__ Eg,  float* __restrict__ E2g,
                                           float* __restrict__ Sg,  float* __restrict__ S2g,
                                           unsigned* __restrict__ amT,
                                           unsigned* __restrict__ cnt) {
    __shared__ float sred[4 * 16];
    __shared__ float dred[4 * 16];

    const int t = threadIdx.x;
    const int w = t >> 6, lane = t & 63;
    const int nl = lane & 15, quad = lane >> 4;
    const int row0 = blockIdx.x * 16;
    const int b = row0 >> 11, jloc0 = row0 & 2047;
    const int gr = row0 + nl;
    const int nt0 = w * 2;  // wave's ntiles: nt0, nt0+1

    if (blockIdx.x == 0) cnt[t] = 0;   // 256 merge counters for k_attn

    // ---- adj pack: 2 rows/block; wave -> (row w>>1, seg half w&1) ----
    {
        const int prow = blockIdx.x * 2 + (w >> 1);
        const int* __restrict__ ar = adj + (size_t)prow * NN;
        const int s0 = (w & 1) * 16;
        #pragma unroll
        for (int s = 0; s < 16; ++s) {
            const int seg = s0 + s;
            const unsigned long long m = __ballot(ar[seg * 64 + lane] != 0);
            if (lane == 0)  amT[(size_t)(seg * 2) * NN + prow] = (unsigned)m;
            if (lane == 32) amT[(size_t)(seg * 2 + 1) * NN + prow] = (unsigned)(m >> 32);
        }
    }

    f32x4 acc[2] = {{0.f,0.f,0.f,0.f},{0.f,0.f,0.f,0.f}};

    #pragma unroll
    for (int ks = 0; ks < 4; ++ks) {
        // x A-frags
        const float4 xa = *reinterpret_cast<const float4*>(&x[(size_t)gr * FF + ks * 32 + quad * 8]);
        const float4 xb = *reinterpret_cast<const float4*>(&x[(size_t)gr * FF + ks * 32 + quad * 8 + 4]);
        const float xv[8] = {xa.x, xa.y, xa.z, xa.w, xb.x, xb.y, xb.z, xb.w};
        half8 ah, al;
        #pragma unroll
        for (int i = 0; i < 8; ++i) {
            const _Float16 hh = (_Float16)xv[i];
            ah[i] = hh;
            al[i] = (_Float16)(xv[i] - (float)hh);
        }
        // W B-frags derived in-register: B[k][n], k = ks*32 + quad*8 + j
        #pragma unroll
        for (int nn = 0; nn < 2; ++nn) {
            const float* __restrict__ wp = W + (size_t)(ks * 32 + quad * 8) * FF + (nt0 + nn) * 16 + nl;
            half8 bh, bl;
            #pragma unroll
            for (int j = 0; j < 8; ++j) {
                const float wv = wp[j * FF];
                const _Float16 hh = (_Float16)wv;
                bh[j] = hh;
                bl[j] = (_Float16)(wv - (float)hh);
            }
            acc[nn] = __builtin_amdgcn_mfma_f32_16x16x32_f16(ah, bh, acc[nn], 0, 0, 0);
            acc[nn] = __builtin_amdgcn_mfma_f32_16x16x32_f16(al, bh, acc[nn], 0, 0, 0);
            acc[nn] = __builtin_amdgcn_mfma_f32_16x16x32_f16(ah, bl, acc[nn], 0, 0, 0);
        }
    }

    // ---- h store: fp16 plane, B-frag layout [b][nt][jg][n][u] ----
    const int jloc = jloc0 + quad * 4;
    const int jg = jloc >> 3, u0 = jloc & 7;   // u0 in {0,4}
    #pragma unroll
    for (int nn = 0; nn < 2; ++nn) {
        ushort4 hv;
        hv.x = h2u((_Float16)acc[nn][0]);
        hv.y = h2u((_Float16)acc[nn][1]);
        hv.z = h2u((_Float16)acc[nn][2]);
        hv.w = h2u((_Float16)acc[nn][3]);
        *reinterpret_cast<ushort4*>(&hF[(size_t)b * 262144 + (nt0 + nn) * 32768 + jg * 128 + nl * 8 + u0]) = hv;
    }

    // ---- s_src / s_dst partials over this wave's 32 cols ----
    float as[2], ad[2];
    #pragma unroll
    for (int nn = 0; nn < 2; ++nn) {
        const int col = (nt0 + nn) * 16 + nl;
        as[nn] = a_src[col];
        ad[nn] = a_dst[col];
    }
    #pragma unroll
    for (int r = 0; r < 4; ++r) {
        float sp = acc[0][r] * as[0] + acc[1][r] * as[1];
        float dp = acc[0][r] * ad[0] + acc[1][r] * ad[1];
        #pragma unroll
        for (int off = 8; off >= 1; off >>= 1) {
            sp += __shfl_xor(sp, off, 16);
            dp += __shfl_xor(dp, off, 16);
        }
        if (nl == 0) {
            sred[w * 16 + quad * 4 + r] = sp;
            dred[w * 16 + quad * 4 + r] = dp;
        }
    }
    __syncthreads();
    if (t < 16) {
        const float sp = sred[t] + sred[16 + t] + sred[32 + t] + sred[48 + t];
        const float dp = dred[t] + dred[16 + t] + dred[32 + t] + dred[48 + t];
        const int row = row0 + t;
        Sg[row]  = __expf(sp - 2.f);
        S2g[row] = __expf(0.2f * sp - 2.f);
        Eg[row]  = __expf(dp - 2.f);
        E2g[row] = __expf(0.2f * dp - 2.f);
    }
}

// ---------------------------------------------------------------------------
// k_attn: p = mask ? max(Si*Ej, S2i*E2j) : 0  (= exp(lrelu(si+sj) - 4)).
// grid (32, 8, 4): 1024 blocks x 512 thr, LDS ~26 KB -> 4 blocks/CU =
// 32 waves/CU (full occupancy). Block: 64 rows x 128 cols x 512 j (8 tiles
// of 64). Ones-column MFMA gives row-sum partials. Each block writes its
// P/L partial; the LAST block per (i0,b) tile (device-scope counter +
// threadfence protocol) merges all 4 partials, normalizes, writes out.
// ---------------------------------------------------------------------------
__global__ __launch_bounds__(512, 4) void k_attn(const unsigned short* __restrict__ hF,
                                                 const unsigned* __restrict__ amT,
                                                 const float* __restrict__ Eg,
                                                 const float* __restrict__ E2g,
                                                 const float* __restrict__ Sg,
                                                 const float* __restrict__ S2g,
                                                 float* __restrict__ P,
                                                 float* __restrict__ L,
                                                 unsigned* __restrict__ cnt,
                                                 float* __restrict__ out) {
    __shared__ float E_l[512];                   // 2 KB (this j-quarter)
    __shared__ float E2_l[512];                  // 2 KB
    __shared__ unsigned am_l[16 * 64];           // 4 KB  [jw][row]
    __shared__ unsigned short pA[2 * 64 * 72];   // 18 KB
    __shared__ int last_s;

    const int t = threadIdx.x;
    const int b = blockIdx.y;
    const int i0 = blockIdx.x * 64;
    const int jh = blockIdx.z;
    const int jbase = jh * 512;

    // ---- stage E/E2 quarter-row, quarter mask ----
    E_l[t]  = Eg[(size_t)b * NN + jbase + t];
    E2_l[t] = E2g[(size_t)b * NN + jbase + t];
    #pragma unroll
    for (int k = 0; k < 2; ++k) {
        const int idx = k * 512 + t;             // 0..1023 = jw(16) x row(64)
        am_l[idx] = amT[(size_t)(jh * 16 + (idx >> 6)) * NN + i0 + (idx & 63)];
    }
    __syncthreads();

    // ---- p-gen ids: thread = rows {2rp, 2rp+1} x 4 j ----
    const int rp = t >> 4, jw4 = t & 15;
    const int ra = rp * 2, rb = ra + 1;
    const float Sa  = Sg[(size_t)b * NN + i0 + ra];
    const float S2a = S2g[(size_t)b * NN + i0 + ra];
    const float Sb  = Sg[(size_t)b * NN + i0 + rb];
    const float S2b = S2g[(size_t)b * NN + i0 + rb];
    const int bitb = (jw4 & 7) * 4;
    const int pwo = ra * 72 + jw4 * 4;

    // ---- MFMA ids: wave = mtiles {mtp, mtp+2} x ntiles {ntp, ntp+4} ----
    const int w = t >> 6, lane = t & 63;
    const int nl = lane & 15, quad = lane >> 4;
    const int mtp = w & 1, ntp = w >> 1;
    const unsigned short* __restrict__ hFb = hF + (size_t)b * 262144;
    int bofs[2], aofs[2];
    #pragma unroll
    for (int nn = 0; nn < 2; ++nn) bofs[nn] = (ntp + nn * 4) * 32768 + (jbase + quad * 8) * 16 + nl * 8;
    #pragma unroll
    for (int mm = 0; mm < 2; ++mm) aofs[mm] = ((mtp + mm * 2) * 16 + nl) * 72 + quad * 8;

    f32x4 acc[2][2] = {{{0.f,0.f,0.f,0.f},{0.f,0.f,0.f,0.f}},{{0.f,0.f,0.f,0.f},{0.f,0.f,0.f,0.f}}};
    f32x4 lac[2] = {{0.f,0.f,0.f,0.f},{0.f,0.f,0.f,0.f}};
    half8 ones;
    #pragma unroll
    for (int i = 0; i < 8; ++i) ones[i] = (_Float16)1.f;

    for (int tt = 0; tt < 8; ++tt) {
        const int buf = tt & 1;
        const int jofs = tt * 1024;              // 64 j x 16 ushort per j-group

        half8 bfr[2][2];
        #pragma unroll
        for (int nn = 0; nn < 2; ++nn) {
            bfr[nn][0] = *reinterpret_cast<const half8*>(hFb + bofs[nn] + jofs);
            bfr[nn][1] = *reinterpret_cast<const half8*>(hFb + bofs[nn] + jofs + 512);
        }

        // ---- p-gen: 2 rows x 4 j ----
        {
            const int jb = tt * 64 + jw4 * 4;    // local j in this quarter
            const float4 ej4  = *reinterpret_cast<const float4*>(&E_l[jb]);
            const float4 e2j4 = *reinterpret_cast<const float4*>(&E2_l[jb]);
            const uint2 mw = *reinterpret_cast<const uint2*>(&am_l[(tt * 2 + (jw4 >> 3)) * 64 + ra]);
            const float ejA[4]  = {ej4.x, ej4.y, ej4.z, ej4.w};
            const float e2jA[4] = {e2j4.x, e2j4.y, e2j4.z, e2j4.w};
            ushort4 ha, hb;
            #pragma unroll
            for (int jj = 0; jj < 4; ++jj) {
                const float ua = fmaxf(Sa * ejA[jj], S2a * e2jA[jj]);
                const float ub = fmaxf(Sb * ejA[jj], S2b * e2jA[jj]);
                const float pa = ((mw.x >> (bitb + jj)) & 1u) ? ua : 0.f;
                const float pb = ((mw.y >> (bitb + jj)) & 1u) ? ub : 0.f;
                ((unsigned short*)&ha)[jj] = h2u((_Float16)pa);
                ((unsigned short*)&hb)[jj] = h2u((_Float16)pb);
            }
            *reinterpret_cast<ushort4*>(&pA[buf * 4608 + pwo]) = ha;
            *reinterpret_cast<ushort4*>(&pA[buf * 4608 + pwo + 72]) = hb;
        }

        __syncthreads();

        half8 afr[2][2];
        #pragma unroll
        for (int mm = 0; mm < 2; ++mm) {
            afr[mm][0] = *reinterpret_cast<const half8*>(&pA[buf * 4608 + aofs[mm]]);
            afr[mm][1] = *reinterpret_cast<const half8*>(&pA[buf * 4608 + aofs[mm] + 32]);
        }
        #pragma unroll
        for (int mm = 0; mm < 2; ++mm) {
            #pragma unroll
            for (int kh = 0; kh < 2; ++kh) {
                lac[mm] = __builtin_amdgcn_mfma_f32_16x16x32_f16(afr[mm][kh], ones, lac[mm], 0, 0, 0);
                acc[mm][0] = __builtin_amdgcn_mfma_f32_16x16x32_f16(afr[mm][kh], bfr[0][kh], acc[mm][0], 0, 0, 0);
                acc[mm][1] = __builtin_amdgcn_mfma_f32_16x16x32_f16(afr[mm][kh], bfr[1][kh], acc[mm][1], 0, 0, 0);
            }
        }
    }

    // ---- write this block's unnormalized partial ----
    float* __restrict__ Pb = P + ((size_t)jh * BATCH + b) * 262144;
    float* __restrict__ Lb = L + ((size_t)jh * BATCH + b) * 2048;
    #pragma unroll
    for (int mm = 0; mm < 2; ++mm) {
        const int lrow = (mtp + mm * 2) * 16 + quad * 4;
        #pragma unroll
        for (int r = 0; r < 4; ++r) {
            #pragma unroll
            for (int nn = 0; nn < 2; ++nn) {
                const int col = (ntp + nn * 4) * 16 + nl;
                Pb[(size_t)(i0 + lrow + r) * FF + col] = acc[mm][nn][r];
            }
            if (nl == 0 && ntp == 0) Lb[i0 + lrow + r] = lac[mm][r];
        }
    }

    // ---- last block per (i0,b) merges (threadFenceReduction pattern) ----
    __threadfence();
    __syncthreads();
    if (t == 0) {
        const unsigned old = atomicAdd(&cnt[b * 32 + blockIdx.x], 1u);
        last_s = (old == 3u);
    }
    __syncthreads();
    if (last_s) {
        __threadfence();
        const int row = t >> 3;                  // 0..63
        const int cg = (t & 7) * 16;             // 0,16,..,112
        float l = 0.f;
        #pragma unroll
        for (int q = 0; q < 4; ++q) l += L[((size_t)q * BATCH + b) * 2048 + i0 + row];
        const float inv = (l > 0.f) ? 1.f / l : 0.f;
        float4 s[4] = {{0,0,0,0},{0,0,0,0},{0,0,0,0},{0,0,0,0}};
        #pragma unroll
        for (int q = 0; q < 4; ++q) {
            const float* __restrict__ Pp = P + ((size_t)q * BATCH + b) * 262144 + (size_t)(i0 + row) * FF + cg;
            #pragma unroll
            for (int v = 0; v < 4; ++v) {
                const float4 pv = *reinterpret_cast<const float4*>(&Pp[v * 4]);
                s[v].x += pv.x; s[v].y += pv.y; s[v].z += pv.z; s[v].w += pv.w;
            }
        }
        float* __restrict__ op = out + ((size_t)b * NN + i0 + row) * FF + cg;
        #pragma unroll
        for (int v = 0; v < 4; ++v) {
            *reinterpret_cast<float4*>(&op[v * 4]) =
                make_float4(s[v].x * inv, s[v].y * inv, s[v].z * inv, s[v].w * inv);
        }
    }
}

extern "C" void kernel_launch(void* const* d_in, const int* in_sizes, int n_in,
                              void* d_out, int out_size, void* d_ws, size_t ws_size,
                              hipStream_t stream) {
    const float* x     = (const float*)d_in[0];
    const int*   adj   = (const int*)d_in[1];
    const float* W     = (const float*)d_in[2];
    const float* a_src = (const float*)d_in[3];
    const float* a_dst = (const float*)d_in[4];
    float* out = (float*)d_out;

    unsigned short* hF = (unsigned short*)d_ws;           // 4 MB
    float* Eg  = (float*)(hF + 2097152);                  // 64 KB
    float* E2g = Eg + 16384;                              // 64 KB
    float* Sg  = E2g + 16384;                             // 64 KB
    float* S2g = Sg + 16384;                              // 64 KB
    unsigned* amT = (unsigned*)(S2g + 16384);             // 512 KB
    float* P = (float*)(amT + 131072);                    // 32 MB  [4][8][2048][128]
    float* L = P + 8388608;                               // 256 KB [4][8][2048]
    unsigned* cnt = (unsigned*)(L + 65536);               // 1 KB   [8][32]

    k_h<<<1024, 256, 0, stream>>>(x, adj, W, a_src, a_dst, hF, Eg, E2g, Sg, S2g, amT, cnt);
    k_attn<<<dim3(32, BATCH, 4), 512, 0, stream>>>(hF, amT, Eg, E2g, Sg, S2g, P, L, cnt, out);
}

// Round 11
// 157.152 us; speedup vs baseline: 2.5148x; 2.5148x over previous
//
#include <hip/hip_runtime.h>
#include <math.h>

#define BATCH 8
#define NN 2048
#define FF 128

typedef __attribute__((ext_vector_type(4))) float f32x4;
typedef _Float16 half8 __attribute__((ext_vector_type(8)));

__device__ __forceinline__ unsigned short h2u(_Float16 h) {
    return __builtin_bit_cast(unsigned short, h);
}

// ---------------------------------------------------------------------------
// k_h: h = x@W via fp16-split MFMA (xh*Wh + xl*Wh + xh*Wl) with W fragments
// derived IN-REGISTER from fp32 W (W is L1/L2-resident; no prep kernel).
// 1024 blocks x 256 thr = 4 blocks/CU: block = 16 rows x 128 cols; wave =
// 16 rows x 32 cols (2 ntiles). h stored as one fp16 plane in B-frag layout;
// epilogue: factored exponentials Sg/S2g/Eg/E2g.
// Each block also packs 2 adj rows -> transposed bitmask amT[jw][i] (ballot).
// NOTE (R10 lesson): NO device-scope fences anywhere — ~300us L2-flush storm.
// ---------------------------------------------------------------------------
__global__ __launch_bounds__(256) void k_h(const float* __restrict__ x,
                                           const int* __restrict__ adj,
                                           const float* __restrict__ W,
                                           const float* __restrict__ a_src,
                                           const float* __restrict__ a_dst,
                                           unsigned short* __restrict__ hF,
                                           float* __restrict__ Eg,  float* __restrict__ E2g,
                                           float* __restrict__ Sg,  float* __restrict__ S2g,
                                           unsigned* __restrict__ amT) {
    __shared__ float sred[4 * 16];
    __shared__ float dred[4 * 16];

    const int t = threadIdx.x;
    const int w = t >> 6, lane = t & 63;
    const int nl = lane & 15, quad = lane >> 4;
    const int row0 = blockIdx.x * 16;
    const int b = row0 >> 11, jloc0 = row0 & 2047;
    const int gr = row0 + nl;
    const int nt0 = w * 2;  // wave's ntiles: nt0, nt0+1

    // ---- adj pack: 2 rows/block; wave -> (row w>>1, seg half w&1) ----
    {
        const int prow = blockIdx.x * 2 + (w >> 1);
        const int* __restrict__ ar = adj + (size_t)prow * NN;
        const int s0 = (w & 1) * 16;
        #pragma unroll
        for (int s = 0; s < 16; ++s) {
            const int seg = s0 + s;
            const unsigned long long m = __ballot(ar[seg * 64 + lane] != 0);
            if (lane == 0)  amT[(size_t)(seg * 2) * NN + prow] = (unsigned)m;
            if (lane == 32) amT[(size_t)(seg * 2 + 1) * NN + prow] = (unsigned)(m >> 32);
        }
    }

    f32x4 acc[2] = {{0.f,0.f,0.f,0.f},{0.f,0.f,0.f,0.f}};

    #pragma unroll
    for (int ks = 0; ks < 4; ++ks) {
        // x A-frags
        const float4 xa = *reinterpret_cast<const float4*>(&x[(size_t)gr * FF + ks * 32 + quad * 8]);
        const float4 xb = *reinterpret_cast<const float4*>(&x[(size_t)gr * FF + ks * 32 + quad * 8 + 4]);
        const float xv[8] = {xa.x, xa.y, xa.z, xa.w, xb.x, xb.y, xb.z, xb.w};
        half8 ah, al;
        #pragma unroll
        for (int i = 0; i < 8; ++i) {
            const _Float16 hh = (_Float16)xv[i];
            ah[i] = hh;
            al[i] = (_Float16)(xv[i] - (float)hh);
        }
        // W B-frags derived in-register: B[k][n], k = ks*32 + quad*8 + j
        #pragma unroll
        for (int nn = 0; nn < 2; ++nn) {
            const float* __restrict__ wp = W + (size_t)(ks * 32 + quad * 8) * FF + (nt0 + nn) * 16 + nl;
            half8 bh, bl;
            #pragma unroll
            for (int j = 0; j < 8; ++j) {
                const float wv = wp[j * FF];
                const _Float16 hh = (_Float16)wv;
                bh[j] = hh;
                bl[j] = (_Float16)(wv - (float)hh);
            }
            acc[nn] = __builtin_amdgcn_mfma_f32_16x16x32_f16(ah, bh, acc[nn], 0, 0, 0);
            acc[nn] = __builtin_amdgcn_mfma_f32_16x16x32_f16(al, bh, acc[nn], 0, 0, 0);
            acc[nn] = __builtin_amdgcn_mfma_f32_16x16x32_f16(ah, bl, acc[nn], 0, 0, 0);
        }
    }

    // ---- h store: fp16 plane, B-frag layout [b][nt][jg][n][u] ----
    const int jloc = jloc0 + quad * 4;
    const int jg = jloc >> 3, u0 = jloc & 7;   // u0 in {0,4}
    #pragma unroll
    for (int nn = 0; nn < 2; ++nn) {
        ushort4 hv;
        hv.x = h2u((_Float16)acc[nn][0]);
        hv.y = h2u((_Float16)acc[nn][1]);
        hv.z = h2u((_Float16)acc[nn][2]);
        hv.w = h2u((_Float16)acc[nn][3]);
        *reinterpret_cast<ushort4*>(&hF[(size_t)b * 262144 + (nt0 + nn) * 32768 + jg * 128 + nl * 8 + u0]) = hv;
    }

    // ---- s_src / s_dst partials over this wave's 32 cols ----
    float as[2], ad[2];
    #pragma unroll
    for (int nn = 0; nn < 2; ++nn) {
        const int col = (nt0 + nn) * 16 + nl;
        as[nn] = a_src[col];
        ad[nn] = a_dst[col];
    }
    #pragma unroll
    for (int r = 0; r < 4; ++r) {
        float sp = acc[0][r] * as[0] + acc[1][r] * as[1];
        float dp = acc[0][r] * ad[0] + acc[1][r] * ad[1];
        #pragma unroll
        for (int off = 8; off >= 1; off >>= 1) {
            sp += __shfl_xor(sp, off, 16);
            dp += __shfl_xor(dp, off, 16);
        }
        if (nl == 0) {
            sred[w * 16 + quad * 4 + r] = sp;
            dred[w * 16 + quad * 4 + r] = dp;
        }
    }
    __syncthreads();
    if (t < 16) {
        const float sp = sred[t] + sred[16 + t] + sred[32 + t] + sred[48 + t];
        const float dp = dred[t] + dred[16 + t] + dred[32 + t] + dred[48 + t];
        const int row = row0 + t;
        Sg[row]  = __expf(sp - 2.f);
        S2g[row] = __expf(0.2f * sp - 2.f);
        Eg[row]  = __expf(dp - 2.f);
        E2g[row] = __expf(0.2f * dp - 2.f);
    }
}

// ---------------------------------------------------------------------------
// k_attn: p = mask ? max(Si*Ej, S2i*E2j) : 0  (= exp(lrelu(si+sj) - 4)).
// grid (32, 8, 4): 1024 blocks x 512 thr, LDS ~26 KB -> 4 blocks/CU =
// 32 waves/CU (full occupancy). Block: 64 rows x 128 cols x 512 j (8 tiles
// of 64). Ones-column MFMA gives row-sum partials. Writes UNNORMALIZED P/L
// partials; k_comb (separate dispatch = implicit device sync) merges.
// ---------------------------------------------------------------------------
__global__ __launch_bounds__(512, 8) void k_attn(const unsigned short* __restrict__ hF,
                                                 const unsigned* __restrict__ amT,
                                                 const float* __restrict__ Eg,
                                                 const float* __restrict__ E2g,
                                                 const float* __restrict__ Sg,
                                                 const float* __restrict__ S2g,
                                                 float* __restrict__ P,
                                                 float* __restrict__ L) {
    __shared__ float E_l[512];                   // 2 KB (this j-quarter)
    __shared__ float E2_l[512];                  // 2 KB
    __shared__ unsigned am_l[16 * 64];           // 4 KB  [jw][row]
    __shared__ unsigned short pA[2 * 64 * 72];   // 18 KB

    const int t = threadIdx.x;
    const int b = blockIdx.y;
    const int i0 = blockIdx.x * 64;
    const int jh = blockIdx.z;
    const int jbase = jh * 512;

    // ---- stage E/E2 quarter-row, quarter mask ----
    E_l[t]  = Eg[(size_t)b * NN + jbase + t];
    E2_l[t] = E2g[(size_t)b * NN + jbase + t];
    #pragma unroll
    for (int k = 0; k < 2; ++k) {
        const int idx = k * 512 + t;             // 0..1023 = jw(16) x row(64)
        am_l[idx] = amT[(size_t)(jh * 16 + (idx >> 6)) * NN + i0 + (idx & 63)];
    }
    __syncthreads();

    // ---- p-gen ids: thread = rows {2rp, 2rp+1} x 4 j ----
    const int rp = t >> 4, jw4 = t & 15;
    const int ra = rp * 2, rb = ra + 1;
    const float Sa  = Sg[(size_t)b * NN + i0 + ra];
    const float S2a = S2g[(size_t)b * NN + i0 + ra];
    const float Sb  = Sg[(size_t)b * NN + i0 + rb];
    const float S2b = S2g[(size_t)b * NN + i0 + rb];
    const int bitb = (jw4 & 7) * 4;
    const int pwo = ra * 72 + jw4 * 4;

    // ---- MFMA ids: wave = mtiles {mtp, mtp+2} x ntiles {ntp, ntp+4} ----
    const int w = t >> 6, lane = t & 63;
    const int nl = lane & 15, quad = lane >> 4;
    const int mtp = w & 1, ntp = w >> 1;
    const unsigned short* __restrict__ hFb = hF + (size_t)b * 262144;
    int bofs[2], aofs[2];
    #pragma unroll
    for (int nn = 0; nn < 2; ++nn) bofs[nn] = (ntp + nn * 4) * 32768 + (jbase + quad * 8) * 16 + nl * 8;
    #pragma unroll
    for (int mm = 0; mm < 2; ++mm) aofs[mm] = ((mtp + mm * 2) * 16 + nl) * 72 + quad * 8;

    f32x4 acc[2][2] = {{{0.f,0.f,0.f,0.f},{0.f,0.f,0.f,0.f}},{{0.f,0.f,0.f,0.f},{0.f,0.f,0.f,0.f}}};
    f32x4 lac[2] = {{0.f,0.f,0.f,0.f},{0.f,0.f,0.f,0.f}};
    half8 ones;
    #pragma unroll
    for (int i = 0; i < 8; ++i) ones[i] = (_Float16)1.f;

    for (int tt = 0; tt < 8; ++tt) {
        const int buf = tt & 1;
        const int jofs = tt * 1024;              // 64 j x 16 ushort per j-group

        half8 bfr[2][2];
        #pragma unroll
        for (int nn = 0; nn < 2; ++nn) {
            bfr[nn][0] = *reinterpret_cast<const half8*>(hFb + bofs[nn] + jofs);
            bfr[nn][1] = *reinterpret_cast<const half8*>(hFb + bofs[nn] + jofs + 512);
        }

        // ---- p-gen: 2 rows x 4 j ----
        {
            const int jb = tt * 64 + jw4 * 4;    // local j in this quarter
            const float4 ej4  = *reinterpret_cast<const float4*>(&E_l[jb]);
            const float4 e2j4 = *reinterpret_cast<const float4*>(&E2_l[jb]);
            const uint2 mw = *reinterpret_cast<const uint2*>(&am_l[(tt * 2 + (jw4 >> 3)) * 64 + ra]);
            const float ejA[4]  = {ej4.x, ej4.y, ej4.z, ej4.w};
            const float e2jA[4] = {e2j4.x, e2j4.y, e2j4.z, e2j4.w};
            ushort4 ha, hb;
            #pragma unroll
            for (int jj = 0; jj < 4; ++jj) {
                const float ua = fmaxf(Sa * ejA[jj], S2a * e2jA[jj]);
                const float ub = fmaxf(Sb * ejA[jj], S2b * e2jA[jj]);
                const float pa = ((mw.x >> (bitb + jj)) & 1u) ? ua : 0.f;
                const float pb = ((mw.y >> (bitb + jj)) & 1u) ? ub : 0.f;
                ((unsigned short*)&ha)[jj] = h2u((_Float16)pa);
                ((unsigned short*)&hb)[jj] = h2u((_Float16)pb);
            }
            *reinterpret_cast<ushort4*>(&pA[buf * 4608 + pwo]) = ha;
            *reinterpret_cast<ushort4*>(&pA[buf * 4608 + pwo + 72]) = hb;
        }

        __syncthreads();

        half8 afr[2][2];
        #pragma unroll
        for (int mm = 0; mm < 2; ++mm) {
            afr[mm][0] = *reinterpret_cast<const half8*>(&pA[buf * 4608 + aofs[mm]]);
            afr[mm][1] = *reinterpret_cast<const half8*>(&pA[buf * 4608 + aofs[mm] + 32]);
        }
        #pragma unroll
        for (int mm = 0; mm < 2; ++mm) {
            #pragma unroll
            for (int kh = 0; kh < 2; ++kh) {
                lac[mm] = __builtin_amdgcn_mfma_f32_16x16x32_f16(afr[mm][kh], ones, lac[mm], 0, 0, 0);
                acc[mm][0] = __builtin_amdgcn_mfma_f32_16x16x32_f16(afr[mm][kh], bfr[0][kh], acc[mm][0], 0, 0, 0);
                acc[mm][1] = __builtin_amdgcn_mfma_f32_16x16x32_f16(afr[mm][kh], bfr[1][kh], acc[mm][1], 0, 0, 0);
            }
        }
    }

    // ---- write this block's unnormalized partial ----
    float* __restrict__ Pb = P + ((size_t)jh * BATCH + b) * 262144;
    float* __restrict__ Lb = L + ((size_t)jh * BATCH + b) * 2048;
    #pragma unroll
    for (int mm = 0; mm < 2; ++mm) {
        const int lrow = (mtp + mm * 2) * 16 + quad * 4;
        #pragma unroll
        for (int r = 0; r < 4; ++r) {
            #pragma unroll
            for (int nn = 0; nn < 2; ++nn) {
                const int col = (ntp + nn * 4) * 16 + nl;
                Pb[(size_t)(i0 + lrow + r) * FF + col] = acc[mm][nn][r];
            }
            if (nl == 0 && ntp == 0) Lb[i0 + lrow + r] = lac[mm][r];
        }
    }
}

// ---------------------------------------------------------------------------
// k_comb: out = (P0+P1+P2+P3) / (L0+L1+L2+L3); rows with no neighbors -> 0.
// 1024 blocks x 256 thr; thread = 2 float4. All inputs L3-resident.
// ---------------------------------------------------------------------------
__global__ __launch_bounds__(256) void k_comb(const float* __restrict__ P,
                                              const float* __restrict__ L,
                                              float* __restrict__ out) {
    const int g0 = blockIdx.x * 512 + threadIdx.x;
    #pragma unroll
    for (int it = 0; it < 2; ++it) {
        const int g = g0 + it * 256;             // float4 index, 0..524287
        const size_t flat = (size_t)g * 4;
        const int row = (int)(flat >> 7);        // 0..16383 (b*2048 + n)
        const float l = L[row] + L[16384 + row] + L[32768 + row] + L[49152 + row];
        const float inv = (l > 0.f) ? 1.f / l : 0.f;
        const float4 p0 = *reinterpret_cast<const float4*>(&P[flat]);
        const float4 p1 = *reinterpret_cast<const float4*>(&P[2097152 + flat]);
        const float4 p2 = *reinterpret_cast<const float4*>(&P[4194304 + flat]);
        const float4 p3 = *reinterpret_cast<const float4*>(&P[6291456 + flat]);
        *reinterpret_cast<float4*>(&out[flat]) =
            make_float4((p0.x + p1.x + p2.x + p3.x) * inv,
                        (p0.y + p1.y + p2.y + p3.y) * inv,
                        (p0.z + p1.z + p2.z + p3.z) * inv,
                        (p0.w + p1.w + p2.w + p3.w) * inv);
    }
}

extern "C" void kernel_launch(void* const* d_in, const int* in_sizes, int n_in,
                              void* d_out, int out_size, void* d_ws, size_t ws_size,
                              hipStream_t stream) {
    const float* x     = (const float*)d_in[0];
    const int*   adj   = (const int*)d_in[1];
    const float* W     = (const float*)d_in[2];
    const float* a_src = (const float*)d_in[3];
    const float* a_dst = (const float*)d_in[4];
    float* out = (float*)d_out;

    unsigned short* hF = (unsigned short*)d_ws;           // 4 MB
    float* Eg  = (float*)(hF + 2097152);                  // 64 KB
    float* E2g = Eg + 16384;                              // 64 KB
    float* Sg  = E2g + 16384;                             // 64 KB
    float* S2g = Sg + 16384;                              // 64 KB
    unsigned* amT = (unsigned*)(S2g + 16384);             // 512 KB
    float* P = (float*)(amT + 131072);                    // 32 MB  [4][8][2048][128]
    float* L = P + 8388608;                               // 256 KB [4][8][2048]

    k_h<<<1024, 256, 0, stream>>>(x, adj, W, a_src, a_dst, hF, Eg, E2g, Sg, S2g, amT);
    k_attn<<<dim3(32, BATCH, 4), 512, 0, stream>>>(hF, amT, Eg, E2g, Sg, S2g, P, L);
    k_comb<<<1024, 256, 0, stream>>>(P, L, out);
}

// Round 12
// 113.847 us; speedup vs baseline: 3.4713x; 1.3804x over previous
//
#include <hip/hip_runtime.h>
#include <math.h>

#define BATCH 8
#define NN 2048
#define FF 128

typedef __attribute__((ext_vector_type(4))) float f32x4;
typedef _Float16 half8 __attribute__((ext_vector_type(8)));

__device__ __forceinline__ unsigned short h2u(_Float16 h) {
    return __builtin_bit_cast(unsigned short, h);
}

// ---------------------------------------------------------------------------
// k_h: h = x@W via fp16-split MFMA (xh*Wh + xl*Wh + xh*Wl) with W fragments
// derived IN-REGISTER from fp32 W (W is L1/L2-resident; no prep kernel).
// 1024 blocks x 256 thr = 4 blocks/CU: block = 16 rows x 128 cols; wave =
// 16 rows x 32 cols (2 ntiles). h stored as one fp16 plane in B-frag layout;
// epilogue: factored exponentials Sg/S2g/Eg/E2g.
// Each block also packs 2 adj rows -> transposed bitmask amT[jw][i] (ballot).
// R10 lesson: NO device-scope fences (L2-flush storm, ~300us).
// R11 lesson: NO launch_bounds waves/EU=8 (64-VGPR cap -> accumulator spill).
// ---------------------------------------------------------------------------
__global__ __launch_bounds__(256) void k_h(const float* __restrict__ x,
                                           const int* __restrict__ adj,
                                           const float* __restrict__ W,
                                           const float* __restrict__ a_src,
                                           const float* __restrict__ a_dst,
                                           unsigned short* __restrict__ hF,
                                           float* __restrict__ Eg,  float* __restrict__ E2g,
                                           float* __restrict__ Sg,  float* __restrict__ S2g,
                                           unsigned* __restrict__ amT) {
    __shared__ float sred[4 * 16];
    __shared__ float dred[4 * 16];

    const int t = threadIdx.x;
    const int w = t >> 6, lane = t & 63;
    const int nl = lane & 15, quad = lane >> 4;
    const int row0 = blockIdx.x * 16;
    const int b = row0 >> 11, jloc0 = row0 & 2047;
    const int gr = row0 + nl;
    const int nt0 = w * 2;  // wave's ntiles: nt0, nt0+1

    // ---- adj pack: 2 rows/block; wave -> (row w>>1, seg half w&1) ----
    {
        const int prow = blockIdx.x * 2 + (w >> 1);
        const int* __restrict__ ar = adj + (size_t)prow * NN;
        const int s0 = (w & 1) * 16;
        #pragma unroll
        for (int s = 0; s < 16; ++s) {
            const int seg = s0 + s;
            const unsigned long long m = __ballot(ar[seg * 64 + lane] != 0);
            if (lane == 0)  amT[(size_t)(seg * 2) * NN + prow] = (unsigned)m;
            if (lane == 32) amT[(size_t)(seg * 2 + 1) * NN + prow] = (unsigned)(m >> 32);
        }
    }

    f32x4 acc[2] = {{0.f,0.f,0.f,0.f},{0.f,0.f,0.f,0.f}};

    #pragma unroll
    for (int ks = 0; ks < 4; ++ks) {
        // x A-frags
        const float4 xa = *reinterpret_cast<const float4*>(&x[(size_t)gr * FF + ks * 32 + quad * 8]);
        const float4 xb = *reinterpret_cast<const float4*>(&x[(size_t)gr * FF + ks * 32 + quad * 8 + 4]);
        const float xv[8] = {xa.x, xa.y, xa.z, xa.w, xb.x, xb.y, xb.z, xb.w};
        half8 ah, al;
        #pragma unroll
        for (int i = 0; i < 8; ++i) {
            const _Float16 hh = (_Float16)xv[i];
            ah[i] = hh;
            al[i] = (_Float16)(xv[i] - (float)hh);
        }
        // W B-frags derived in-register: B[k][n], k = ks*32 + quad*8 + j
        #pragma unroll
        for (int nn = 0; nn < 2; ++nn) {
            const float* __restrict__ wp = W + (size_t)(ks * 32 + quad * 8) * FF + (nt0 + nn) * 16 + nl;
            half8 bh, bl;
            #pragma unroll
            for (int j = 0; j < 8; ++j) {
                const float wv = wp[j * FF];
                const _Float16 hh = (_Float16)wv;
                bh[j] = hh;
                bl[j] = (_Float16)(wv - (float)hh);
            }
            acc[nn] = __builtin_amdgcn_mfma_f32_16x16x32_f16(ah, bh, acc[nn], 0, 0, 0);
            acc[nn] = __builtin_amdgcn_mfma_f32_16x16x32_f16(al, bh, acc[nn], 0, 0, 0);
            acc[nn] = __builtin_amdgcn_mfma_f32_16x16x32_f16(ah, bl, acc[nn], 0, 0, 0);
        }
    }

    // ---- h store: fp16 plane, B-frag layout [b][nt][jg][n][u] ----
    const int jloc = jloc0 + quad * 4;
    const int jg = jloc >> 3, u0 = jloc & 7;   // u0 in {0,4}
    #pragma unroll
    for (int nn = 0; nn < 2; ++nn) {
        ushort4 hv;
        hv.x = h2u((_Float16)acc[nn][0]);
        hv.y = h2u((_Float16)acc[nn][1]);
        hv.z = h2u((_Float16)acc[nn][2]);
        hv.w = h2u((_Float16)acc[nn][3]);
        *reinterpret_cast<ushort4*>(&hF[(size_t)b * 262144 + (nt0 + nn) * 32768 + jg * 128 + nl * 8 + u0]) = hv;
    }

    // ---- s_src / s_dst partials over this wave's 32 cols ----
    float as[2], ad[2];
    #pragma unroll
    for (int nn = 0; nn < 2; ++nn) {
        const int col = (nt0 + nn) * 16 + nl;
        as[nn] = a_src[col];
        ad[nn] = a_dst[col];
    }
    #pragma unroll
    for (int r = 0; r < 4; ++r) {
        float sp = acc[0][r] * as[0] + acc[1][r] * as[1];
        float dp = acc[0][r] * ad[0] + acc[1][r] * ad[1];
        #pragma unroll
        for (int off = 8; off >= 1; off >>= 1) {
            sp += __shfl_xor(sp, off, 16);
            dp += __shfl_xor(dp, off, 16);
        }
        if (nl == 0) {
            sred[w * 16 + quad * 4 + r] = sp;
            dred[w * 16 + quad * 4 + r] = dp;
        }
    }
    __syncthreads();
    if (t < 16) {
        const float sp = sred[t] + sred[16 + t] + sred[32 + t] + sred[48 + t];
        const float dp = dred[t] + dred[16 + t] + dred[32 + t] + dred[48 + t];
        const int row = row0 + t;
        Sg[row]  = __expf(sp - 2.f);
        S2g[row] = __expf(0.2f * sp - 2.f);
        Eg[row]  = __expf(dp - 2.f);
        E2g[row] = __expf(0.2f * dp - 2.f);
    }
}

// ---------------------------------------------------------------------------
// k_attn: p = mask ? max(Si*Ej, S2i*E2j) : 0  (= exp(lrelu(si+sj) - 4)).
// grid (32, 8, 4): 1024 blocks x 512 thr, LDS ~26 KB, ~48 VGPR -> HW can
// pack 4 blocks/CU (32 waves) on its own. launch_bounds min-waves stays 4:
// asking for 8 caps VGPRs at 64 and spills the accumulators (R11: 148 MB
// scratch writes, 65 us). Block: 64 rows x 128 cols x 512 j (8 tiles of 64).
// Ones-column MFMA gives row-sum partials. Writes UNNORMALIZED P/L partials;
// k_comb (separate dispatch = implicit device sync) merges.
// ---------------------------------------------------------------------------
__global__ __launch_bounds__(512, 4) void k_attn(const unsigned short* __restrict__ hF,
                                                 const unsigned* __restrict__ amT,
                                                 const float* __restrict__ Eg,
                                                 const float* __restrict__ E2g,
                                                 const float* __restrict__ Sg,
                                                 const float* __restrict__ S2g,
                                                 float* __restrict__ P,
                                                 float* __restrict__ L) {
    __shared__ float E_l[512];                   // 2 KB (this j-quarter)
    __shared__ float E2_l[512];                  // 2 KB
    __shared__ unsigned am_l[16 * 64];           // 4 KB  [jw][row]
    __shared__ unsigned short pA[2 * 64 * 72];   // 18 KB

    const int t = threadIdx.x;
    const int b = blockIdx.y;
    const int i0 = blockIdx.x * 64;
    const int jh = blockIdx.z;
    const int jbase = jh * 512;

    // ---- stage E/E2 quarter-row, quarter mask ----
    E_l[t]  = Eg[(size_t)b * NN + jbase + t];
    E2_l[t] = E2g[(size_t)b * NN + jbase + t];
    #pragma unroll
    for (int k = 0; k < 2; ++k) {
        const int idx = k * 512 + t;             // 0..1023 = jw(16) x row(64)
        am_l[idx] = amT[(size_t)(jh * 16 + (idx >> 6)) * NN + i0 + (idx & 63)];
    }
    __syncthreads();

    // ---- p-gen ids: thread = rows {2rp, 2rp+1} x 4 j ----
    const int rp = t >> 4, jw4 = t & 15;
    const int ra = rp * 2, rb = ra + 1;
    const float Sa  = Sg[(size_t)b * NN + i0 + ra];
    const float S2a = S2g[(size_t)b * NN + i0 + ra];
    const float Sb  = Sg[(size_t)b * NN + i0 + rb];
    const float S2b = S2g[(size_t)b * NN + i0 + rb];
    const int bitb = (jw4 & 7) * 4;
    const int pwo = ra * 72 + jw4 * 4;

    // ---- MFMA ids: wave = mtiles {mtp, mtp+2} x ntiles {ntp, ntp+4} ----
    const int w = t >> 6, lane = t & 63;
    const int nl = lane & 15, quad = lane >> 4;
    const int mtp = w & 1, ntp = w >> 1;
    const unsigned short* __restrict__ hFb = hF + (size_t)b * 262144;
    int bofs[2], aofs[2];
    #pragma unroll
    for (int nn = 0; nn < 2; ++nn) bofs[nn] = (ntp + nn * 4) * 32768 + (jbase + quad * 8) * 16 + nl * 8;
    #pragma unroll
    for (int mm = 0; mm < 2; ++mm) aofs[mm] = ((mtp + mm * 2) * 16 + nl) * 72 + quad * 8;

    f32x4 acc[2][2] = {{{0.f,0.f,0.f,0.f},{0.f,0.f,0.f,0.f}},{{0.f,0.f,0.f,0.f},{0.f,0.f,0.f,0.f}}};
    f32x4 lac[2] = {{0.f,0.f,0.f,0.f},{0.f,0.f,0.f,0.f}};
    half8 ones;
    #pragma unroll
    for (int i = 0; i < 8; ++i) ones[i] = (_Float16)1.f;

    for (int tt = 0; tt < 8; ++tt) {
        const int buf = tt & 1;
        const int jofs = tt * 1024;              // 64 j x 16 ushort per j-group

        half8 bfr[2][2];
        #pragma unroll
        for (int nn = 0; nn < 2; ++nn) {
            bfr[nn][0] = *reinterpret_cast<const half8*>(hFb + bofs[nn] + jofs);
            bfr[nn][1] = *reinterpret_cast<const half8*>(hFb + bofs[nn] + jofs + 512);
        }

        // ---- p-gen: 2 rows x 4 j ----
        {
            const int jb = tt * 64 + jw4 * 4;    // local j in this quarter
            const float4 ej4  = *reinterpret_cast<const float4*>(&E_l[jb]);
            const float4 e2j4 = *reinterpret_cast<const float4*>(&E2_l[jb]);
            const uint2 mw = *reinterpret_cast<const uint2*>(&am_l[(tt * 2 + (jw4 >> 3)) * 64 + ra]);
            const float ejA[4]  = {ej4.x, ej4.y, ej4.z, ej4.w};
            const float e2jA[4] = {e2j4.x, e2j4.y, e2j4.z, e2j4.w};
            ushort4 ha, hb;
            #pragma unroll
            for (int jj = 0; jj < 4; ++jj) {
                const float ua = fmaxf(Sa * ejA[jj], S2a * e2jA[jj]);
                const float ub = fmaxf(Sb * ejA[jj], S2b * e2jA[jj]);
                const float pa = ((mw.x >> (bitb + jj)) & 1u) ? ua : 0.f;
                const float pb = ((mw.y >> (bitb + jj)) & 1u) ? ub : 0.f;
                ((unsigned short*)&ha)[jj] = h2u((_Float16)pa);
                ((unsigned short*)&hb)[jj] = h2u((_Float16)pb);
            }
            *reinterpret_cast<ushort4*>(&pA[buf * 4608 + pwo]) = ha;
            *reinterpret_cast<ushort4*>(&pA[buf * 4608 + pwo + 72]) = hb;
        }

        __syncthreads();

        half8 afr[2][2];
        #pragma unroll
        for (int mm = 0; mm < 2; ++mm) {
            afr[mm][0] = *reinterpret_cast<const half8*>(&pA[buf * 4608 + aofs[mm]]);
            afr[mm][1] = *reinterpret_cast<const half8*>(&pA[buf * 4608 + aofs[mm] + 32]);
        }
        #pragma unroll
        for (int mm = 0; mm < 2; ++mm) {
            #pragma unroll
            for (int kh = 0; kh < 2; ++kh) {
                lac[mm] = __builtin_amdgcn_mfma_f32_16x16x32_f16(afr[mm][kh], ones, lac[mm], 0, 0, 0);
                acc[mm][0] = __builtin_amdgcn_mfma_f32_16x16x32_f16(afr[mm][kh], bfr[0][kh], acc[mm][0], 0, 0, 0);
                acc[mm][1] = __builtin_amdgcn_mfma_f32_16x16x32_f16(afr[mm][kh], bfr[1][kh], acc[mm][1], 0, 0, 0);
            }
        }
    }

    // ---- write this block's unnormalized partial ----
    float* __restrict__ Pb = P + ((size_t)jh * BATCH + b) * 262144;
    float* __restrict__ Lb = L + ((size_t)jh * BATCH + b) * 2048;
    #pragma unroll
    for (int mm = 0; mm < 2; ++mm) {
        const int lrow = (mtp + mm * 2) * 16 + quad * 4;
        #pragma unroll
        for (int r = 0; r < 4; ++r) {
            #pragma unroll
            for (int nn = 0; nn < 2; ++nn) {
                const int col = (ntp + nn * 4) * 16 + nl;
                Pb[(size_t)(i0 + lrow + r) * FF + col] = acc[mm][nn][r];
            }
            if (nl == 0 && ntp == 0) Lb[i0 + lrow + r] = lac[mm][r];
        }
    }
}

// ---------------------------------------------------------------------------
// k_comb: out = (P0+P1+P2+P3) / (L0+L1+L2+L3); rows with no neighbors -> 0.
// 1024 blocks x 256 thr; thread = 2 float4. All inputs L3-resident.
// ---------------------------------------------------------------------------
__global__ __launch_bounds__(256) void k_comb(const float* __restrict__ P,
                                              const float* __restrict__ L,
                                              float* __restrict__ out) {
    const int g0 = blockIdx.x * 512 + threadIdx.x;
    #pragma unroll
    for (int it = 0; it < 2; ++it) {
        const int g = g0 + it * 256;             // float4 index, 0..524287
        const size_t flat = (size_t)g * 4;
        const int row = (int)(flat >> 7);        // 0..16383 (b*2048 + n)
        const float l = L[row] + L[16384 + row] + L[32768 + row] + L[49152 + row];
        const float inv = (l > 0.f) ? 1.f / l : 0.f;
        const float4 p0 = *reinterpret_cast<const float4*>(&P[flat]);
        const float4 p1 = *reinterpret_cast<const float4*>(&P[2097152 + flat]);
        const float4 p2 = *reinterpret_cast<const float4*>(&P[4194304 + flat]);
        const float4 p3 = *reinterpret_cast<const float4*>(&P[6291456 + flat]);
        *reinterpret_cast<float4*>(&out[flat]) =
            make_float4((p0.x + p1.x + p2.x + p3.x) * inv,
                        (p0.y + p1.y + p2.y + p3.y) * inv,
                        (p0.z + p1.z + p2.z + p3.z) * inv,
                        (p0.w + p1.w + p2.w + p3.w) * inv);
    }
}

extern "C" void kernel_launch(void* const* d_in, const int* in_sizes, int n_in,
                              void* d_out, int out_size, void* d_ws, size_t ws_size,
                              hipStream_t stream) {
    const float* x     = (const float*)d_in[0];
    const int*   adj   = (const int*)d_in[1];
    const float* W     = (const float*)d_in[2];
    const float* a_src = (const float*)d_in[3];
    const float* a_dst = (const float*)d_in[4];
    float* out = (float*)d_out;

    unsigned short* hF = (unsigned short*)d_ws;           // 4 MB
    float* Eg  = (float*)(hF + 2097152);                  // 64 KB
    float* E2g = Eg + 16384;                              // 64 KB
    float* Sg  = E2g + 16384;                             // 64 KB
    float* S2g = Sg + 16384;                              // 64 KB
    unsigned* amT = (unsigned*)(S2g + 16384);             // 512 KB
    float* P = (float*)(amT + 131072);                    // 32 MB  [4][8][2048][128]
    float* L = P + 8388608;                               // 256 KB [4][8][2048]

    k_h<<<1024, 256, 0, stream>>>(x, adj, W, a_src, a_dst, hF, Eg, E2g, Sg, S2g, amT);
    k_attn<<<dim3(32, BATCH, 4), 512, 0, stream>>>(hF, amT, Eg, E2g, Sg, S2g, P, L);
    k_comb<<<1024, 256, 0, stream>>>(P, L, out);
}

// Round 13
// 112.656 us; speedup vs baseline: 3.5080x; 1.0106x over previous
//
#include <hip/hip_runtime.h>
#include <math.h>

#define BATCH 8
#define NN 2048
#define FF 128

typedef __attribute__((ext_vector_type(4))) float f32x4;
typedef _Float16 half8 __attribute__((ext_vector_type(8)));

__device__ __forceinline__ unsigned short h2u(_Float16 h) {
    return __builtin_bit_cast(unsigned short, h);
}

// ---------------------------------------------------------------------------
// k_h: h = x@W via fp16-split MFMA (xh*Wh + xl*Wh + xh*Wl) with W fragments
// derived IN-REGISTER from fp32 W (W is L1/L2-resident; no prep kernel).
// 1024 blocks x 256 thr = 4 blocks/CU: block = 16 rows x 128 cols; wave =
// 16 rows x 32 cols (2 ntiles). h stored as one fp16 plane in B-frag layout;
// epilogue: factored exponentials Sg/S2g/Eg/E2g.
// Each block also packs 2 adj rows -> transposed bitmask amT[jw][i] (ballot).
// R10 lesson: NO device-scope fences (L2-flush storm, ~300us).
// R11 lesson: NO launch_bounds waves/EU=8 (64-VGPR cap -> accumulator spill).
// ---------------------------------------------------------------------------
__global__ __launch_bounds__(256) void k_h(const float* __restrict__ x,
                                           const int* __restrict__ adj,
                                           const float* __restrict__ W,
                                           const float* __restrict__ a_src,
                                           const float* __restrict__ a_dst,
                                           unsigned short* __restrict__ hF,
                                           float* __restrict__ Eg,  float* __restrict__ E2g,
                                           float* __restrict__ Sg,  float* __restrict__ S2g,
                                           unsigned* __restrict__ amT) {
    __shared__ float sred[4 * 16];
    __shared__ float dred[4 * 16];

    const int t = threadIdx.x;
    const int w = t >> 6, lane = t & 63;
    const int nl = lane & 15, quad = lane >> 4;
    const int row0 = blockIdx.x * 16;
    const int b = row0 >> 11, jloc0 = row0 & 2047;
    const int gr = row0 + nl;
    const int nt0 = w * 2;  // wave's ntiles: nt0, nt0+1

    // ---- adj pack: 2 rows/block; wave -> (row w>>1, seg half w&1) ----
    {
        const int prow = blockIdx.x * 2 + (w >> 1);
        const int* __restrict__ ar = adj + (size_t)prow * NN;
        const int s0 = (w & 1) * 16;
        #pragma unroll
        for (int s = 0; s < 16; ++s) {
            const int seg = s0 + s;
            const unsigned long long m = __ballot(ar[seg * 64 + lane] != 0);
            if (lane == 0)  amT[(size_t)(seg * 2) * NN + prow] = (unsigned)m;
            if (lane == 32) amT[(size_t)(seg * 2 + 1) * NN + prow] = (unsigned)(m >> 32);
        }
    }

    f32x4 acc[2] = {{0.f,0.f,0.f,0.f},{0.f,0.f,0.f,0.f}};

    #pragma unroll
    for (int ks = 0; ks < 4; ++ks) {
        // x A-frags
        const float4 xa = *reinterpret_cast<const float4*>(&x[(size_t)gr * FF + ks * 32 + quad * 8]);
        const float4 xb = *reinterpret_cast<const float4*>(&x[(size_t)gr * FF + ks * 32 + quad * 8 + 4]);
        const float xv[8] = {xa.x, xa.y, xa.z, xa.w, xb.x, xb.y, xb.z, xb.w};
        half8 ah, al;
        #pragma unroll
        for (int i = 0; i < 8; ++i) {
            const _Float16 hh = (_Float16)xv[i];
            ah[i] = hh;
            al[i] = (_Float16)(xv[i] - (float)hh);
        }
        // W B-frags derived in-register: B[k][n], k = ks*32 + quad*8 + j
        #pragma unroll
        for (int nn = 0; nn < 2; ++nn) {
            const float* __restrict__ wp = W + (size_t)(ks * 32 + quad * 8) * FF + (nt0 + nn) * 16 + nl;
            half8 bh, bl;
            #pragma unroll
            for (int j = 0; j < 8; ++j) {
                const float wv = wp[j * FF];
                const _Float16 hh = (_Float16)wv;
                bh[j] = hh;
                bl[j] = (_Float16)(wv - (float)hh);
            }
            acc[nn] = __builtin_amdgcn_mfma_f32_16x16x32_f16(ah, bh, acc[nn], 0, 0, 0);
            acc[nn] = __builtin_amdgcn_mfma_f32_16x16x32_f16(al, bh, acc[nn], 0, 0, 0);
            acc[nn] = __builtin_amdgcn_mfma_f32_16x16x32_f16(ah, bl, acc[nn], 0, 0, 0);
        }
    }

    // ---- h store: fp16 plane, B-frag layout [b][nt][jg][n][u] ----
    const int jloc = jloc0 + quad * 4;
    const int jg = jloc >> 3, u0 = jloc & 7;   // u0 in {0,4}
    #pragma unroll
    for (int nn = 0; nn < 2; ++nn) {
        ushort4 hv;
        hv.x = h2u((_Float16)acc[nn][0]);
        hv.y = h2u((_Float16)acc[nn][1]);
        hv.z = h2u((_Float16)acc[nn][2]);
        hv.w = h2u((_Float16)acc[nn][3]);
        *reinterpret_cast<ushort4*>(&hF[(size_t)b * 262144 + (nt0 + nn) * 32768 + jg * 128 + nl * 8 + u0]) = hv;
    }

    // ---- s_src / s_dst partials over this wave's 32 cols ----
    float as[2], ad[2];
    #pragma unroll
    for (int nn = 0; nn < 2; ++nn) {
        const int col = (nt0 + nn) * 16 + nl;
        as[nn] = a_src[col];
        ad[nn] = a_dst[col];
    }
    #pragma unroll
    for (int r = 0; r < 4; ++r) {
        float sp = acc[0][r] * as[0] + acc[1][r] * as[1];
        float dp = acc[0][r] * ad[0] + acc[1][r] * ad[1];
        #pragma unroll
        for (int off = 8; off >= 1; off >>= 1) {
            sp += __shfl_xor(sp, off, 16);
            dp += __shfl_xor(dp, off, 16);
        }
        if (nl == 0) {
            sred[w * 16 + quad * 4 + r] = sp;
            dred[w * 16 + quad * 4 + r] = dp;
        }
    }
    __syncthreads();
    if (t < 16) {
        const float sp = sred[t] + sred[16 + t] + sred[32 + t] + sred[48 + t];
        const float dp = dred[t] + dred[16 + t] + dred[32 + t] + dred[48 + t];
        const int row = row0 + t;
        Sg[row]  = __expf(sp - 2.f);
        S2g[row] = __expf(0.2f * sp - 2.f);
        Eg[row]  = __expf(dp - 2.f);
        E2g[row] = __expf(0.2f * dp - 2.f);
    }
}

// ---------------------------------------------------------------------------
// k_attn: p = mask ? max(Si*Ej, S2i*E2j) : 0  (= exp(lrelu(si+sj) - 4)).
// grid (32, 8, 2): 512 blocks x 512 thr. LDS = pA ONLY (18 KB — E/E2/mask
// read direct from global, L1-broadcast) -> 4 blocks/CU possible by LDS and
// VGPR; 16 j-tiles of 64 per block. l accumulated per-thread in VALU (no
// ones-MFMA: saves 1/3 of MFMAs), one end-of-kernel shuffle reduction.
// Writes UNNORMALIZED P/L partials; k_comb merges (implicit device sync).
// ---------------------------------------------------------------------------
__global__ __launch_bounds__(512, 4) void k_attn(const unsigned short* __restrict__ hF,
                                                 const unsigned* __restrict__ amT,
                                                 const float* __restrict__ Eg,
                                                 const float* __restrict__ E2g,
                                                 const float* __restrict__ Sg,
                                                 const float* __restrict__ S2g,
                                                 float* __restrict__ P,
                                                 float* __restrict__ L) {
    __shared__ unsigned short pA[2 * 64 * 72];   // 18 KB

    const int t = threadIdx.x;
    const int b = blockIdx.y;
    const int i0 = blockIdx.x * 64;
    const int jh = blockIdx.z;                   // 0..1
    const int jbase = jh * 1024;

    // ---- p-gen ids: thread = rows {2rp, 2rp+1} x 4 j ----
    const int rp = t >> 4, jw4 = t & 15;
    const int ra = rp * 2, rb = ra + 1;
    const float Sa  = Sg[(size_t)b * NN + i0 + ra];
    const float S2a = S2g[(size_t)b * NN + i0 + ra];
    const float Sb  = Sg[(size_t)b * NN + i0 + rb];
    const float S2b = S2g[(size_t)b * NN + i0 + rb];
    const int bitb = (jw4 & 7) * 4;
    const int pwo = ra * 72 + jw4 * 4;
    const float* __restrict__ Egb  = Eg  + (size_t)b * NN + jbase;
    const float* __restrict__ E2gb = E2g + (size_t)b * NN + jbase;
    const unsigned* __restrict__ amb = amT + (size_t)(jh * 32) * NN + i0;

    // ---- MFMA ids: wave = mtiles {mtp, mtp+2} x ntiles {ntp, ntp+4} ----
    const int w = t >> 6, lane = t & 63;
    const int nl = lane & 15, quad = lane >> 4;
    const int mtp = w & 1, ntp = w >> 1;
    const unsigned short* __restrict__ hFb = hF + (size_t)b * 262144;
    int bofs[2], aofs[2];
    #pragma unroll
    for (int nn = 0; nn < 2; ++nn) bofs[nn] = (ntp + nn * 4) * 32768 + (jbase + quad * 8) * 16 + nl * 8;
    #pragma unroll
    for (int mm = 0; mm < 2; ++mm) aofs[mm] = ((mtp + mm * 2) * 16 + nl) * 72 + quad * 8;

    f32x4 acc[2][2] = {{{0.f,0.f,0.f,0.f},{0.f,0.f,0.f,0.f}},{{0.f,0.f,0.f,0.f},{0.f,0.f,0.f,0.f}}};
    float la = 0.f, lb = 0.f;

    for (int tt = 0; tt < 16; ++tt) {
        const int buf = tt & 1;
        const int jofs = tt * 1024;              // 64 j x 16 ushort per j-group

        half8 bfr[2][2];
        #pragma unroll
        for (int nn = 0; nn < 2; ++nn) {
            bfr[nn][0] = *reinterpret_cast<const half8*>(hFb + bofs[nn] + jofs);
            bfr[nn][1] = *reinterpret_cast<const half8*>(hFb + bofs[nn] + jofs + 512);
        }

        // ---- p-gen: 2 rows x 4 j (E/E2/mask direct from global) ----
        {
            const int jb = tt * 64 + jw4 * 4;    // local j in this half
            const float4 ej4  = *reinterpret_cast<const float4*>(&Egb[jb]);
            const float4 e2j4 = *reinterpret_cast<const float4*>(&E2gb[jb]);
            const uint2 mw = *reinterpret_cast<const uint2*>(&amb[(size_t)(tt * 2 + (jw4 >> 3)) * NN + ra]);
            const float ejA[4]  = {ej4.x, ej4.y, ej4.z, ej4.w};
            const float e2jA[4] = {e2j4.x, e2j4.y, e2j4.z, e2j4.w};
            ushort4 ha, hb;
            #pragma unroll
            for (int jj = 0; jj < 4; ++jj) {
                const float ua = fmaxf(Sa * ejA[jj], S2a * e2jA[jj]);
                const float ub = fmaxf(Sb * ejA[jj], S2b * e2jA[jj]);
                const float pa = ((mw.x >> (bitb + jj)) & 1u) ? ua : 0.f;
                const float pb = ((mw.y >> (bitb + jj)) & 1u) ? ub : 0.f;
                la += pa;
                lb += pb;
                ((unsigned short*)&ha)[jj] = h2u((_Float16)pa);
                ((unsigned short*)&hb)[jj] = h2u((_Float16)pb);
            }
            *reinterpret_cast<ushort4*>(&pA[buf * 4608 + pwo]) = ha;
            *reinterpret_cast<ushort4*>(&pA[buf * 4608 + pwo + 72]) = hb;
        }

        __syncthreads();

        half8 afr[2][2];
        #pragma unroll
        for (int mm = 0; mm < 2; ++mm) {
            afr[mm][0] = *reinterpret_cast<const half8*>(&pA[buf * 4608 + aofs[mm]]);
            afr[mm][1] = *reinterpret_cast<const half8*>(&pA[buf * 4608 + aofs[mm] + 32]);
        }
        #pragma unroll
        for (int mm = 0; mm < 2; ++mm) {
            #pragma unroll
            for (int kh = 0; kh < 2; ++kh) {
                acc[mm][0] = __builtin_amdgcn_mfma_f32_16x16x32_f16(afr[mm][kh], bfr[0][kh], acc[mm][0], 0, 0, 0);
                acc[mm][1] = __builtin_amdgcn_mfma_f32_16x16x32_f16(afr[mm][kh], bfr[1][kh], acc[mm][1], 0, 0, 0);
            }
        }
    }

    // ---- l reduction over the 16 jw4 threads of each row pair ----
    #pragma unroll
    for (int off = 8; off >= 1; off >>= 1) {
        la += __shfl_xor(la, off, 16);
        lb += __shfl_xor(lb, off, 16);
    }

    // ---- write this block's unnormalized partial ----
    float* __restrict__ Pb = P + ((size_t)jh * BATCH + b) * 262144;
    float* __restrict__ Lb = L + ((size_t)jh * BATCH + b) * 2048;
    if (jw4 == 0) {
        Lb[i0 + ra] = la;
        Lb[i0 + rb] = lb;
    }
    #pragma unroll
    for (int mm = 0; mm < 2; ++mm) {
        const int lrow = (mtp + mm * 2) * 16 + quad * 4;
        #pragma unroll
        for (int r = 0; r < 4; ++r) {
            #pragma unroll
            for (int nn = 0; nn < 2; ++nn) {
                const int col = (ntp + nn * 4) * 16 + nl;
                Pb[(size_t)(i0 + lrow + r) * FF + col] = acc[mm][nn][r];
            }
        }
    }
}

// ---------------------------------------------------------------------------
// k_comb: out = (P0 + P1) / (L0 + L1); rows with no neighbors -> 0.
// 1024 blocks x 256 thr; thread = 2 float4. All inputs L3-resident.
// ---------------------------------------------------------------------------
__global__ __launch_bounds__(256) void k_comb(const float* __restrict__ P,
                                              const float* __restrict__ L,
                                              float* __restrict__ out) {
    const int g0 = blockIdx.x * 512 + threadIdx.x;
    #pragma unroll
    for (int it = 0; it < 2; ++it) {
        const int g = g0 + it * 256;             // float4 index, 0..524287
        const size_t flat = (size_t)g * 4;
        const int row = (int)(flat >> 7);        // 0..16383 (b*2048 + n)
        const float l = L[row] + L[16384 + row];
        const float inv = (l > 0.f) ? 1.f / l : 0.f;
        const float4 p0 = *reinterpret_cast<const float4*>(&P[flat]);
        const float4 p1 = *reinterpret_cast<const float4*>(&P[2097152 + flat]);
        *reinterpret_cast<float4*>(&out[flat]) =
            make_float4((p0.x + p1.x) * inv, (p0.y + p1.y) * inv,
                        (p0.z + p1.z) * inv, (p0.w + p1.w) * inv);
    }
}

extern "C" void kernel_launch(void* const* d_in, const int* in_sizes, int n_in,
                              void* d_out, int out_size, void* d_ws, size_t ws_size,
                              hipStream_t stream) {
    const float* x     = (const float*)d_in[0];
    const int*   adj   = (const int*)d_in[1];
    const float* W     = (const float*)d_in[2];
    const float* a_src = (const float*)d_in[3];
    const float* a_dst = (const float*)d_in[4];
    float* out = (float*)d_out;

    unsigned short* hF = (unsigned short*)d_ws;           // 4 MB
    float* Eg  = (float*)(hF + 2097152);                  // 64 KB
    float* E2g = Eg + 16384;                              // 64 KB
    float* Sg  = E2g + 16384;                             // 64 KB
    float* S2g = Sg + 16384;                              // 64 KB
    unsigned* amT = (unsigned*)(S2g + 16384);             // 512 KB
    float* P = (float*)(amT + 131072);                    // 16 MB  [2][8][2048][128]
    float* L = P + 4194304;                               // 128 KB [2][8][2048]

    k_h<<<1024, 256, 0, stream>>>(x, adj, W, a_src, a_dst, hF, Eg, E2g, Sg, S2g, amT);
    k_attn<<<dim3(32, BATCH, 2), 512, 0, stream>>>(hF, amT, Eg, E2g, Sg, S2g, P, L);
    k_comb<<<1024, 256, 0, stream>>>(P, L, out);
}